// Round 3
// baseline (772.993 us; speedup 1.0000x reference)
//
#include <hip/hip_runtime.h>

#define TPB 256

// ================= linked-list bucket build =================
// For each edge: push e onto dst's list. pack[e] = {prev_head, src[e]}.
// Only scattered traffic is the 4B atomicExch on head[] (400KB, L2-resident);
// pack[] writes are fully coalesced by edge id.
__global__ __launch_bounds__(TPB) void build_ll_kernel(const int* __restrict__ src,
                                                       const int* __restrict__ dst,
                                                       int* __restrict__ head,
                                                       int2* __restrict__ pack, int E) {
    int e = blockIdx.x * TPB + threadIdx.x;
    if (e < E) {
        int d = dst[e];
        int s = src[e];
        int old = atomicExch(&head[d], e);
        pack[e] = make_int2(old, s);
    }
}

// ====== mean aggregation: one wave per dst node, walk the list ======
// 64 lanes cover the 64 cols (one coalesced 256B row read per hop).
// Loop-carried dep = pack[e] read; feat gather overlaps the next pack read.
__global__ __launch_bounds__(TPB) void ll_mean_kernel(const float* __restrict__ feat,
                                                      const int* __restrict__ head,
                                                      const int2* __restrict__ pack,
                                                      float* __restrict__ outm, int n) {
    int w = (int)(((long long)blockIdx.x * TPB + threadIdx.x) >> 6);
    if (w >= n) return;
    const int lane = threadIdx.x & 63;
    int e = head[w];  // lane-uniform -> broadcast
    float acc = 0.0f;
    int cnt = 0;
    while (e >= 0) {
        int2 p = pack[e];  // lane-uniform 8B
        acc += feat[(long long)p.y * 64 + lane];
        ++cnt;
        e = p.x;
    }
    float inv = cnt ? 1.0f / (float)cnt : 0.0f;
    outm[(long long)w * 64 + lane] = acc * inv;
}

// ---- y[g][c] = sum_k x[g][k]*W[c][k]; MODE1: += aggr[g][c] (pre-meaned) + bias[c], relu ----
// Block: 64 nodes x 64 cols, 256 threads, 4x4 register tile per thread.
// LDS exactly 64KB; XOR swizzle for conflict-free reads (no room for padding).
template <int MODE>
__global__ __launch_bounds__(TPB) void lin128to64_kernel(
    const float* __restrict__ x, const float* __restrict__ W,
    const float* __restrict__ aggr, const float* __restrict__ bias,
    float* __restrict__ out, int n) {
    __shared__ float Ws[64 * 128];  // Ws[c*128 + (k ^ (c&31))] = W[c][k]
    __shared__ float xs[64 * 128];  // xs[r*128 + (k ^ ((r&3)<<3))] = x[node0+r][k]
    const int tid = threadIdx.x;
    const int node0 = blockIdx.x * 64;

    for (int idx = tid; idx < 64 * 128; idx += TPB) {
        int r = idx >> 7, k = idx & 127;
        Ws[(r << 7) + (k ^ (r & 31))] = W[idx];
    }
    for (int idx = tid; idx < 64 * 128; idx += TPB) {
        int r = idx >> 7, k = idx & 127;
        int g = node0 + r;
        xs[(r << 7) + (k ^ ((r & 3) << 3))] = (g < n) ? x[(long long)g * 128 + k] : 0.0f;
    }
    __syncthreads();

    const int cg = tid & 15;   // col group: cols cg + 16j
    const int ng = tid >> 4;   // node group: nodes ng + 16i
    float acc[4][4];
#pragma unroll
    for (int i = 0; i < 4; ++i)
#pragma unroll
        for (int j = 0; j < 4; ++j) acc[i][j] = 0.0f;

    const int xsw = (ng & 3) << 3;
    int wbase[4], wsw[4], xbase[4];
#pragma unroll
    for (int j = 0; j < 4; ++j) {
        int c = cg + 16 * j;
        wbase[j] = c << 7;
        wsw[j] = c & 31;
    }
#pragma unroll
    for (int i = 0; i < 4; ++i) xbase[i] = (ng + 16 * i) << 7;

#pragma unroll 4
    for (int k = 0; k < 128; ++k) {
        float xv[4], wv[4];
        int kx = k ^ xsw;
#pragma unroll
        for (int i = 0; i < 4; ++i) xv[i] = xs[xbase[i] + kx];
#pragma unroll
        for (int j = 0; j < 4; ++j) wv[j] = Ws[wbase[j] + (k ^ wsw[j])];
#pragma unroll
        for (int i = 0; i < 4; ++i)
#pragma unroll
            for (int j = 0; j < 4; ++j) acc[i][j] += xv[i] * wv[j];
    }

#pragma unroll
    for (int i = 0; i < 4; ++i) {
        int g = node0 + ng + 16 * i;
        if (g >= n) continue;
#pragma unroll
        for (int j = 0; j < 4; ++j) {
            int c = cg + 16 * j;
            float v = acc[i][j];
            if (MODE == 1) {
                v += aggr[g * 64 + c] + bias[c];
                v = fmaxf(v, 0.0f);
            }
            out[g * 64 + c] = v;
        }
    }
}

// ---- out[g][C] = sum_k m2[g][k]*Wl[C][k] + sum_k h[g][k]*Wr[C][k] + b[C] ----
// m2 already meaned. Block: 64 nodes x 64 cols (gridDim.y picks col half).
__global__ __launch_bounds__(TPB) void out_kernel(
    const float* __restrict__ m2, const float* __restrict__ h,
    const float* __restrict__ Wl, const float* __restrict__ Wr,
    const float* __restrict__ bias, float* __restrict__ out, int n) {
    __shared__ float Wls[64 * 64];  // Wls[c*64 + (k ^ (c&31))] = Wl[chalf+c][k]
    __shared__ float Wrs[64 * 64];
    __shared__ float ams[64 * 64];  // ams[r*64 + k] = m2[node0+r][k]
    __shared__ float hhs[64 * 64];
    const int tid = threadIdx.x;
    const int node0 = blockIdx.x * 64;
    const int chalf = blockIdx.y * 64;

    for (int idx = tid; idx < 64 * 64; idx += TPB) {
        int c = idx >> 6, k = idx & 63;
        int sw = (c << 6) + (k ^ (c & 31));
        Wls[sw] = Wl[(chalf + c) * 64 + k];
        Wrs[sw] = Wr[(chalf + c) * 64 + k];
    }
    for (int idx = tid; idx < 64 * 64; idx += TPB) {
        int r = idx >> 6, k = idx & 63;
        int g = node0 + r;
        float av = 0.0f, hv = 0.0f;
        if (g < n) {
            av = m2[g * 64 + k];
            hv = h[g * 64 + k];
        }
        ams[(r << 6) + k] = av;
        hhs[(r << 6) + k] = hv;
    }
    __syncthreads();

    const int cg = tid & 31;  // cols cg and cg+32 (local)
    const int ng = tid >> 5;  // nodes ng + 8i, i=0..7
    float acc[8][2];
#pragma unroll
    for (int i = 0; i < 8; ++i) { acc[i][0] = 0.0f; acc[i][1] = 0.0f; }
    const int wb0 = cg << 6;
    const int wb1 = (cg + 32) << 6;

#pragma unroll 4
    for (int k = 0; k < 64; ++k) {
        int kk = k ^ cg;  // (cg+32)&31 == cg, same swizzle for both cols
        float wl0 = Wls[wb0 + kk], wl1 = Wls[wb1 + kk];
        float wr0 = Wrs[wb0 + kk], wr1 = Wrs[wb1 + kk];
#pragma unroll
        for (int i = 0; i < 8; ++i) {
            int r = ng + 8 * i;
            float av = ams[(r << 6) + k];
            float hv = hhs[(r << 6) + k];
            acc[i][0] += av * wl0 + hv * wr0;
            acc[i][1] += av * wl1 + hv * wr1;
        }
    }

#pragma unroll
    for (int i = 0; i < 8; ++i) {
        int g = node0 + ng + 8 * i;
        if (g >= n) continue;
        long long base = (long long)g * 128 + chalf;
        out[base + cg] = acc[i][0] + bias[chalf + cg];
        out[base + cg + 32] = acc[i][1] + bias[chalf + cg + 32];
    }
}

extern "C" void kernel_launch(void* const* d_in, const int* in_sizes, int n_in,
                              void* d_out, int out_size, void* d_ws, size_t ws_size,
                              hipStream_t stream) {
    const float* x = (const float*)d_in[0];
    const int* ei = (const int*)d_in[1];
    const float* Wl1 = (const float*)d_in[2];
    const float* Wr1 = (const float*)d_in[3];
    const float* b1 = (const float*)d_in[4];
    const float* Wl2 = (const float*)d_in[5];
    const float* Wr2 = (const float*)d_in[6];
    const float* b2 = (const float*)d_in[7];
    float* out = (float*)d_out;

    const int n = in_sizes[0] / 128;   // 100000
    const int E = in_sizes[1] / 2;     // 1600000
    const int* src = ei;
    const int* dst = ei + E;

    // workspace layout (4B elems, 64-elem aligned):
    // head[n] | pack[E] (int2) | bufA[n*64] | bufB[n*64]
    // buffer liveness: bufA=y1 -> bufB=mean1 -> bufA=h (y1 dead) -> bufB=mean2 (mean1 dead)
    char* wsb = (char*)d_ws;
    auto A = [](size_t v) { return (v + 63) & ~(size_t)63; };
    int* head = (int*)wsb;                         size_t o = A(n);
    int2* pack = (int2*)((int*)wsb + o);           o += A((size_t)E * 2);
    float* bufA = (float*)wsb + o;                 o += (size_t)n * 64;
    float* bufB = (float*)wsb + o;

    // ---- build per-dst linked lists ----
    hipMemsetAsync(head, 0xFF, (size_t)n * sizeof(int), stream);  // head = -1
    build_ll_kernel<<<(E + TPB - 1) / TPB, TPB, 0, stream>>>(src, dst, head, pack, E);

    const int gblocks = (n + 63) / 64;
    const int mblocks = (int)(((long long)n * 64 + TPB - 1) / TPB);

    // y1 = x @ W_l1.T
    lin128to64_kernel<0><<<gblocks, TPB, 0, stream>>>(x, Wl1, nullptr, nullptr, bufA, n);
    // mean1 = ll_mean(y1)
    ll_mean_kernel<<<mblocks, TPB, 0, stream>>>(bufA, head, pack, bufB, n);
    // h = relu(mean1 + b1 + x @ W_r1.T)   (overwrites y1 -- y1 dead)
    lin128to64_kernel<1><<<gblocks, TPB, 0, stream>>>(x, Wr1, bufB, b1, bufA, n);
    // mean2 = ll_mean(h)                  (overwrites mean1 -- mean1 dead)
    ll_mean_kernel<<<mblocks, TPB, 0, stream>>>(bufA, head, pack, bufB, n);
    // out = mean2 @ W_l2.T + b2 + h @ W_r2.T
    dim3 og(gblocks, 2);
    out_kernel<<<og, TPB, 0, stream>>>(bufB, bufA, Wl2, Wr2, b2, out, n);
}

// Round 4
// 656.905 us; speedup vs baseline: 1.1767x; 1.1767x over previous
//
#include <hip/hip_runtime.h>

#define TPB 256

typedef unsigned short ushort_t;
typedef unsigned int uint_t;

__device__ inline ushort_t f2bf(float f) {  // round-to-nearest-even bf16
    uint_t u = __float_as_uint(f);
    return (ushort_t)((u + 0x7FFFu + ((u >> 16) & 1u)) >> 16);
}

// ================= CSR build (by dst) =================

__global__ __launch_bounds__(TPB) void hist_kernel(const int* __restrict__ dst,
                                                   int* __restrict__ cnt, int E) {
    int e = blockIdx.x * TPB + threadIdx.x;
    if (e < E) atomicAdd(&cnt[dst[e]], 1);
}

// per-block (1024-elem) exclusive scan of cnt -> rs, block totals -> bsum
__global__ __launch_bounds__(TPB) void scanA_kernel(const int* __restrict__ cnt,
                                                    int* __restrict__ rs,
                                                    int* __restrict__ bsum, int n) {
    __shared__ int lds[TPB];
    const int t = threadIdx.x;
    const int base = blockIdx.x * 1024 + t * 4;
    int v[4], s = 0;
#pragma unroll
    for (int i = 0; i < 4; ++i) {
        int idx = base + i;
        v[i] = (idx < n) ? cnt[idx] : 0;
        s += v[i];
    }
    lds[t] = s;
    __syncthreads();
    for (int off = 1; off < TPB; off <<= 1) {
        int add = (t >= off) ? lds[t - off] : 0;
        __syncthreads();
        lds[t] += add;
        __syncthreads();
    }
    int run = lds[t] - s;
#pragma unroll
    for (int i = 0; i < 4; ++i) {
        int idx = base + i;
        if (idx < n) rs[idx] = run;
        run += v[i];
    }
    if (t == 0) bsum[blockIdx.x] = lds[TPB - 1];
}

// single block: exclusive scan of bsum (nb <= 256); also set rs[n] = E
__global__ __launch_bounds__(TPB) void scanB_kernel(int* __restrict__ bsum, int nb,
                                                    int* __restrict__ rs, int n, int E) {
    __shared__ int lds[TPB];
    const int t = threadIdx.x;
    int s = (t < nb) ? bsum[t] : 0;
    lds[t] = s;
    __syncthreads();
    for (int off = 1; off < TPB; off <<= 1) {
        int add = (t >= off) ? lds[t - off] : 0;
        __syncthreads();
        lds[t] += add;
        __syncthreads();
    }
    if (t < nb) bsum[t] = lds[t] - s;
    if (t == 0) rs[n] = E;
}

// add block offsets; also init cursor (aliases cnt array) = row start
__global__ __launch_bounds__(TPB) void scanC_kernel(int* __restrict__ rs,
                                                    const int* __restrict__ bsum,
                                                    int* __restrict__ cursor, int n) {
    int idx = blockIdx.x * TPB + threadIdx.x;
    if (idx < n) {
        int v = rs[idx] + bsum[idx >> 10];
        rs[idx] = v;
        cursor[idx] = v;
    }
}

__global__ __launch_bounds__(TPB) void fill_kernel(const int* __restrict__ src,
                                                   const int* __restrict__ dst,
                                                   int* __restrict__ cursor,
                                                   int* __restrict__ perm, int E) {
    int e = blockIdx.x * TPB + threadIdx.x;
    if (e < E) {
        int p = atomicAdd(&cursor[dst[e]], 1);
        __builtin_nontemporal_store(src[e], &perm[p]);  // avoid write-allocate thrash
    }
}

// ====== mean aggregation over bf16 feature rows, via CSR ======
// One wave per dst node. lane = o*8 + cl: oct o handles edge slot e+o (8 rows
// in flight per wave for MLP), lane cl covers 16B = 8 bf16 cols. f32 accumulate,
// 3-round shfl_xor reduce, f32 output row (256B coalesced).
__global__ __launch_bounds__(TPB) void csr_mean_bf16_kernel(
    const ushort_t* __restrict__ feat, const int* __restrict__ rs,
    const int* __restrict__ perm, float* __restrict__ outm, int n) {
    int w = (int)(((long long)blockIdx.x * TPB + threadIdx.x) >> 6);
    if (w >= n) return;
    const int lane = threadIdx.x & 63;
    const int o = lane >> 3;
    const int cl = lane & 7;
    const int beg = rs[w], end = rs[w + 1];
    float acc[8];
#pragma unroll
    for (int j = 0; j < 8; ++j) acc[j] = 0.0f;
    for (int e = beg + o; e < end; e += 8) {
        int s = perm[e];
        uint4 v = ((const uint4*)(feat + (long long)s * 64))[cl];
        acc[0] += __uint_as_float(v.x << 16);
        acc[1] += __uint_as_float(v.x & 0xFFFF0000u);
        acc[2] += __uint_as_float(v.y << 16);
        acc[3] += __uint_as_float(v.y & 0xFFFF0000u);
        acc[4] += __uint_as_float(v.z << 16);
        acc[5] += __uint_as_float(v.z & 0xFFFF0000u);
        acc[6] += __uint_as_float(v.w << 16);
        acc[7] += __uint_as_float(v.w & 0xFFFF0000u);
    }
#pragma unroll
    for (int off = 8; off < 64; off <<= 1)
#pragma unroll
        for (int j = 0; j < 8; ++j) acc[j] += __shfl_xor(acc[j], off, 64);
    if (lane < 8) {
        float d = (float)(end - beg);
        float inv = d > 0.f ? 1.f / d : 0.f;
        float4* dptr = (float4*)(outm + (long long)w * 64 + cl * 8);
        dptr[0] = make_float4(acc[0] * inv, acc[1] * inv, acc[2] * inv, acc[3] * inv);
        dptr[1] = make_float4(acc[4] * inv, acc[5] * inv, acc[6] * inv, acc[7] * inv);
    }
}

// ---- y[g][c] = sum_k x[g][k]*W[c][k] ----
// MODE0: write bf16 only (y1). MODE1: v += aggr+bias, relu; write f32 h AND bf16 hb.
// Block: 64 nodes x 64 cols, 256 threads, 4x4 register tile per thread.
// LDS exactly 64KB; XOR swizzle for conflict-free reads.
template <int MODE>
__global__ __launch_bounds__(TPB) void lin128to64_kernel(
    const float* __restrict__ x, const float* __restrict__ W,
    const float* __restrict__ aggr, const float* __restrict__ bias,
    float* __restrict__ outf, ushort_t* __restrict__ outb, int n) {
    __shared__ float Ws[64 * 128];  // Ws[c*128 + (k ^ (c&31))] = W[c][k]
    __shared__ float xs[64 * 128];  // xs[r*128 + (k ^ ((r&3)<<3))] = x[node0+r][k]
    const int tid = threadIdx.x;
    const int node0 = blockIdx.x * 64;

    for (int idx = tid; idx < 64 * 128; idx += TPB) {
        int r = idx >> 7, k = idx & 127;
        Ws[(r << 7) + (k ^ (r & 31))] = W[idx];
    }
    for (int idx = tid; idx < 64 * 128; idx += TPB) {
        int r = idx >> 7, k = idx & 127;
        int g = node0 + r;
        xs[(r << 7) + (k ^ ((r & 3) << 3))] = (g < n) ? x[(long long)g * 128 + k] : 0.0f;
    }
    __syncthreads();

    const int cg = tid & 15;   // col group: cols cg + 16j
    const int ng = tid >> 4;   // node group: nodes ng + 16i
    float acc[4][4];
#pragma unroll
    for (int i = 0; i < 4; ++i)
#pragma unroll
        for (int j = 0; j < 4; ++j) acc[i][j] = 0.0f;

    const int xsw = (ng & 3) << 3;
    int wbase[4], wsw[4], xbase[4];
#pragma unroll
    for (int j = 0; j < 4; ++j) {
        int c = cg + 16 * j;
        wbase[j] = c << 7;
        wsw[j] = c & 31;
    }
#pragma unroll
    for (int i = 0; i < 4; ++i) xbase[i] = (ng + 16 * i) << 7;

#pragma unroll 4
    for (int k = 0; k < 128; ++k) {
        float xv[4], wv[4];
        int kx = k ^ xsw;
#pragma unroll
        for (int i = 0; i < 4; ++i) xv[i] = xs[xbase[i] + kx];
#pragma unroll
        for (int j = 0; j < 4; ++j) wv[j] = Ws[wbase[j] + (k ^ wsw[j])];
#pragma unroll
        for (int i = 0; i < 4; ++i)
#pragma unroll
            for (int j = 0; j < 4; ++j) acc[i][j] += xv[i] * wv[j];
    }

#pragma unroll
    for (int i = 0; i < 4; ++i) {
        int g = node0 + ng + 16 * i;
        if (g >= n) continue;
#pragma unroll
        for (int j = 0; j < 4; ++j) {
            int c = cg + 16 * j;
            float v = acc[i][j];
            if (MODE == 1) {
                v += aggr[g * 64 + c] + bias[c];
                v = fmaxf(v, 0.0f);
                outf[(long long)g * 64 + c] = v;
            }
            outb[(long long)g * 64 + c] = f2bf(v);
        }
    }
}

// ---- out[g][C] = sum_k m2[g][k]*Wl[C][k] + sum_k h[g][k]*Wr[C][k] + b[C] ----
// m2 already meaned. Block: 64 nodes x 64 cols (gridDim.y picks col half).
__global__ __launch_bounds__(TPB) void out_kernel(
    const float* __restrict__ m2, const float* __restrict__ h,
    const float* __restrict__ Wl, const float* __restrict__ Wr,
    const float* __restrict__ bias, float* __restrict__ out, int n) {
    __shared__ float Wls[64 * 64];  // Wls[c*64 + (k ^ (c&31))] = Wl[chalf+c][k]
    __shared__ float Wrs[64 * 64];
    __shared__ float ams[64 * 64];  // ams[r*64 + k] = m2[node0+r][k]
    __shared__ float hhs[64 * 64];
    const int tid = threadIdx.x;
    const int node0 = blockIdx.x * 64;
    const int chalf = blockIdx.y * 64;

    for (int idx = tid; idx < 64 * 64; idx += TPB) {
        int c = idx >> 6, k = idx & 63;
        int sw = (c << 6) + (k ^ (c & 31));
        Wls[sw] = Wl[(chalf + c) * 64 + k];
        Wrs[sw] = Wr[(chalf + c) * 64 + k];
    }
    for (int idx = tid; idx < 64 * 64; idx += TPB) {
        int r = idx >> 6, k = idx & 63;
        int g = node0 + r;
        float av = 0.0f, hv = 0.0f;
        if (g < n) {
            av = m2[(long long)g * 64 + k];
            hv = h[(long long)g * 64 + k];
        }
        ams[(r << 6) + k] = av;
        hhs[(r << 6) + k] = hv;
    }
    __syncthreads();

    const int cg = tid & 31;  // cols cg and cg+32 (local)
    const int ng = tid >> 5;  // nodes ng + 8i, i=0..7
    float acc[8][2];
#pragma unroll
    for (int i = 0; i < 8; ++i) { acc[i][0] = 0.0f; acc[i][1] = 0.0f; }
    const int wb0 = cg << 6;
    const int wb1 = (cg + 32) << 6;

#pragma unroll 4
    for (int k = 0; k < 64; ++k) {
        int kk = k ^ cg;  // (cg+32)&31 == cg, same swizzle for both cols
        float wl0 = Wls[wb0 + kk], wl1 = Wls[wb1 + kk];
        float wr0 = Wrs[wb0 + kk], wr1 = Wrs[wb1 + kk];
#pragma unroll
        for (int i = 0; i < 8; ++i) {
            int r = ng + 8 * i;
            float av = ams[(r << 6) + k];
            float hv = hhs[(r << 6) + k];
            acc[i][0] += av * wl0 + hv * wr0;
            acc[i][1] += av * wl1 + hv * wr1;
        }
    }

#pragma unroll
    for (int i = 0; i < 8; ++i) {
        int g = node0 + ng + 8 * i;
        if (g >= n) continue;
        long long base = (long long)g * 128 + chalf;
        out[base + cg] = acc[i][0] + bias[chalf + cg];
        out[base + cg + 32] = acc[i][1] + bias[chalf + cg + 32];
    }
}

extern "C" void kernel_launch(void* const* d_in, const int* in_sizes, int n_in,
                              void* d_out, int out_size, void* d_ws, size_t ws_size,
                              hipStream_t stream) {
    const float* x = (const float*)d_in[0];
    const int* ei = (const int*)d_in[1];
    const float* Wl1 = (const float*)d_in[2];
    const float* Wr1 = (const float*)d_in[3];
    const float* b1 = (const float*)d_in[4];
    const float* Wl2 = (const float*)d_in[5];
    const float* Wr2 = (const float*)d_in[6];
    const float* b2 = (const float*)d_in[7];
    float* out = (float*)d_out;

    const int n = in_sizes[0] / 128;   // 100000
    const int E = in_sizes[1] / 2;     // 1600000
    const int* src = ei;
    const int* dst = ei + E;

    // workspace (4B units, 64-aligned):
    // cnt/cursor[n] | rs[n+1] | bsum[256] | perm[E] | y1b/hb (n*64 bf16 = n*32 ints)
    //   | meanf[n*64 f32] | h[n*64 f32]
    // liveness: y1b dead after mean1 -> hb aliases it. meanf reused for mean1 then mean2.
    char* wsb = (char*)d_ws;
    auto A = [](size_t v) { return (v + 63) & ~(size_t)63; };
    int* cnt = (int*)wsb;                          size_t o = A(n);
    int* rs = (int*)wsb + o;                       o += A(n + 1);
    int* bsum = (int*)wsb + o;                     o += 256;
    int* perm = (int*)wsb + o;                     o += A(E);
    ushort_t* fb = (ushort_t*)((int*)wsb + o);     o += A((size_t)n * 32);  // y1b / hb
    float* meanf = (float*)wsb + o;                o += (size_t)n * 64;
    float* h = (float*)wsb + o;

    // ---- CSR build (by dst) ----
    hipMemsetAsync(cnt, 0, (size_t)n * sizeof(int), stream);
    hist_kernel<<<(E + TPB - 1) / TPB, TPB, 0, stream>>>(dst, cnt, E);
    const int nb = (n + 1023) / 1024;  // 98
    scanA_kernel<<<nb, TPB, 0, stream>>>(cnt, rs, bsum, n);
    scanB_kernel<<<1, TPB, 0, stream>>>(bsum, nb, rs, n, E);
    scanC_kernel<<<(n + TPB - 1) / TPB, TPB, 0, stream>>>(rs, bsum, cnt, n);
    fill_kernel<<<(E + TPB - 1) / TPB, TPB, 0, stream>>>(src, dst, cnt, perm, E);

    const int gblocks = (n + 63) / 64;
    const int mblocks = (int)(((long long)n * 64 + TPB - 1) / TPB);

    // y1b = bf16(x @ W_l1.T)
    lin128to64_kernel<0><<<gblocks, TPB, 0, stream>>>(x, Wl1, nullptr, nullptr,
                                                      nullptr, fb, n);
    // meanf = csr_mean(y1b)
    csr_mean_bf16_kernel<<<mblocks, TPB, 0, stream>>>(fb, rs, perm, meanf, n);
    // h = relu(meanf + b1 + x @ W_r1.T); hb = bf16(h) (overwrites y1b -- dead)
    lin128to64_kernel<1><<<gblocks, TPB, 0, stream>>>(x, Wr1, meanf, b1, h, fb, n);
    // meanf = csr_mean(hb) (meanf dead after lin<1>)
    csr_mean_bf16_kernel<<<mblocks, TPB, 0, stream>>>(fb, rs, perm, meanf, n);
    // out = meanf @ W_l2.T + b2 + h @ W_r2.T
    dim3 og(gblocks, 2);
    out_kernel<<<og, TPB, 0, stream>>>(meanf, h, Wl2, Wr2, b2, out, n);
}

// Round 5
// 504.168 us; speedup vs baseline: 1.5332x; 1.3029x over previous
//
#include <hip/hip_runtime.h>

#define TPB 256
#define BK_SH 8           // 256 nodes per bucket
#define NBMAX 512         // max buckets (n <= 131072)
#define TILE 4096         // edges per bin_scatter tile
#define CAP 8192          // LDS staging capacity per bucket (records)

typedef unsigned short ushort_t;
typedef unsigned int uint_t;

__device__ inline ushort_t f2bf(float f) {  // round-to-nearest-even bf16
    uint_t u = __float_as_uint(f);
    return (ushort_t)((u + 0x7FFFu + ((u >> 16) & 1u)) >> 16);
}

// ========== K1: bucket histogram (dst >> 8), LDS-aggregated ==========
__global__ __launch_bounds__(TPB) void bucket_hist_kernel(const int* __restrict__ dst,
                                                          int* __restrict__ bcnt,
                                                          int E, int NB) {
    __shared__ int h[NBMAX];
    for (int i = threadIdx.x; i < NBMAX; i += TPB) h[i] = 0;
    __syncthreads();
    int stride = gridDim.x * TPB;
    for (int e = blockIdx.x * TPB + threadIdx.x; e < E; e += stride)
        atomicAdd(&h[dst[e] >> BK_SH], 1);
    __syncthreads();
    for (int i = threadIdx.x; i < NB; i += TPB)
        if (h[i]) atomicAdd(&bcnt[i], h[i]);
}

// ========== K2: scan bucket counts -> bases + cursors; rs[n] = E ==========
__global__ __launch_bounds__(NBMAX) void bucket_scan_kernel(const int* __restrict__ bcnt,
                                                            int* __restrict__ bbase,
                                                            int* __restrict__ bcursor,
                                                            int NB, int* __restrict__ rs,
                                                            int n, int E) {
    __shared__ int s[NBMAX];
    const int t = threadIdx.x;
    int v = (t < NB) ? bcnt[t] : 0;
    s[t] = v;
    __syncthreads();
    for (int off = 1; off < NBMAX; off <<= 1) {
        int a = (t >= off) ? s[t - off] : 0;
        __syncthreads();
        s[t] += a;
        __syncthreads();
    }
    if (t < NB) { int ex = s[t] - v; bbase[t] = ex; bcursor[t] = ex; }
    if (t == 0) rs[n] = E;
}

// ========== K3: tile-sort edges by bucket in LDS, flush contiguous runs ==========
// record = (src << 8) | (dst & 255)   [src < 2^24 assumed; here src < 2^17]
__global__ __launch_bounds__(TPB) void bin_scatter_kernel(const int* __restrict__ src,
                                                          const int* __restrict__ dst,
                                                          int* __restrict__ bcursor,
                                                          uint_t* __restrict__ recs,
                                                          int E, int NB) {
    __shared__ uint_t rec[TILE];
    __shared__ ushort_t bb[TILE];
    __shared__ int hist[NBMAX];
    __shared__ int start[NBMAX];
    __shared__ int cur[NBMAX];
    __shared__ int gbase[NBMAX];
    __shared__ int ss[TPB];
    const int tid = threadIdx.x;
    const int t0 = blockIdx.x * TILE;
    const int cnt = min(TILE, E - t0);
    for (int i = tid; i < NBMAX; i += TPB) hist[i] = 0;
    __syncthreads();

    int myS[16], myD[16];
#pragma unroll
    for (int j = 0; j < 16; ++j) {
        int e = t0 + j * TPB + tid;
        if (e < E) {
            myS[j] = src[e];
            myD[j] = dst[e];
            atomicAdd(&hist[myD[j] >> BK_SH], 1);
        } else {
            myD[j] = -1;
        }
    }
    __syncthreads();

    // exclusive scan of hist[512] with 256 threads (2 elems/thread)
    int h0 = hist[2 * tid], h1 = hist[2 * tid + 1];
    int sum2 = h0 + h1;
    ss[tid] = sum2;
    __syncthreads();
    for (int off = 1; off < TPB; off <<= 1) {
        int a = (tid >= off) ? ss[tid - off] : 0;
        __syncthreads();
        ss[tid] += a;
        __syncthreads();
    }
    int ex = ss[tid] - sum2;
    start[2 * tid] = ex;
    start[2 * tid + 1] = ex + h0;
    cur[2 * tid] = ex;
    cur[2 * tid + 1] = ex + h0;
    __syncthreads();

    // place records into LDS grouped by bucket
#pragma unroll
    for (int j = 0; j < 16; ++j) {
        if (myD[j] >= 0) {
            int b = myD[j] >> BK_SH;
            int p = atomicAdd(&cur[b], 1);
            rec[p] = ((uint_t)myS[j] << BK_SH) | (uint_t)(myD[j] & ((1 << BK_SH) - 1));
            bb[p] = (ushort_t)b;
        }
    }
    __syncthreads();

    // reserve a contiguous global run per bucket
    for (int b = tid; b < NB; b += TPB) {
        int c = hist[b];
        gbase[b] = c ? atomicAdd(&bcursor[b], c) : 0;
    }
    __syncthreads();

    // flush: consecutive i within a bucket -> consecutive global addresses
    for (int i = tid; i < cnt; i += TPB) {
        int b = bb[i];
        recs[gbase[b] + (i - start[b])] = rec[i];
    }
}

// ========== K4: per-bucket: per-node counts, rs, build perm in LDS, flush ==========
__global__ __launch_bounds__(TPB) void bucket_build_kernel(const uint_t* __restrict__ recs,
                                                           const int* __restrict__ bbase,
                                                           const int* __restrict__ bcnt,
                                                           int* __restrict__ rs,
                                                           int* __restrict__ perm, int n) {
    __shared__ int nh[TPB];
    __shared__ int ncur[TPB];
    __shared__ int sscan[TPB];
    __shared__ uint_t stage[CAP];
    const int b = blockIdx.x;
    const int tid = threadIdx.x;
    const int gb = bbase[b];
    const int cnt = bcnt[b];
    nh[tid] = 0;
    __syncthreads();
    for (int i = tid; i < cnt; i += TPB)
        atomicAdd(&nh[recs[gb + i] & 255], 1);
    __syncthreads();
    int v = nh[tid];
    sscan[tid] = v;
    __syncthreads();
    for (int off = 1; off < TPB; off <<= 1) {
        int a = (tid >= off) ? sscan[tid - off] : 0;
        __syncthreads();
        sscan[tid] += a;
        __syncthreads();
    }
    int ex = sscan[tid] - v;
    int g = (b << BK_SH) + tid;
    if (g < n) rs[g] = gb + ex;
    ncur[tid] = ex;
    __syncthreads();
    if (cnt <= CAP) {
        for (int i = tid; i < cnt; i += TPB) {
            uint_t r = recs[gb + i];
            int p = atomicAdd(&ncur[r & 255], 1);
            stage[p] = r >> BK_SH;
        }
        __syncthreads();
        for (int i = tid; i < cnt; i += TPB)
            perm[gb + i] = (int)stage[i];
    } else {  // fallback (never for uniform-random dst)
        for (int i = tid; i < cnt; i += TPB) {
            uint_t r = recs[gb + i];
            int p = atomicAdd(&ncur[r & 255], 1);
            perm[gb + p] = (int)(r >> BK_SH);
        }
    }
}

// ====== mean aggregation over bf16 feature rows, via CSR ======
// One wave per dst node. lane = o*8 + cl: oct o handles edge slot e+o (8 rows
// in flight per wave for MLP), lane cl covers 16B = 8 bf16 cols.
__global__ __launch_bounds__(TPB) void csr_mean_bf16_kernel(
    const ushort_t* __restrict__ feat, const int* __restrict__ rs,
    const int* __restrict__ perm, float* __restrict__ outm, int n) {
    int w = (int)(((long long)blockIdx.x * TPB + threadIdx.x) >> 6);
    if (w >= n) return;
    const int lane = threadIdx.x & 63;
    const int o = lane >> 3;
    const int cl = lane & 7;
    const int beg = rs[w], end = rs[w + 1];
    float acc[8];
#pragma unroll
    for (int j = 0; j < 8; ++j) acc[j] = 0.0f;
    for (int e = beg + o; e < end; e += 8) {
        int s = perm[e];
        uint4 v = ((const uint4*)(feat + (long long)s * 64))[cl];
        acc[0] += __uint_as_float(v.x << 16);
        acc[1] += __uint_as_float(v.x & 0xFFFF0000u);
        acc[2] += __uint_as_float(v.y << 16);
        acc[3] += __uint_as_float(v.y & 0xFFFF0000u);
        acc[4] += __uint_as_float(v.z << 16);
        acc[5] += __uint_as_float(v.z & 0xFFFF0000u);
        acc[6] += __uint_as_float(v.w << 16);
        acc[7] += __uint_as_float(v.w & 0xFFFF0000u);
    }
#pragma unroll
    for (int off = 8; off < 64; off <<= 1)
#pragma unroll
        for (int j = 0; j < 8; ++j) acc[j] += __shfl_xor(acc[j], off, 64);
    if (lane < 8) {
        float d = (float)(end - beg);
        float inv = d > 0.f ? 1.f / d : 0.f;
        float4* dptr = (float4*)(outm + (long long)w * 64 + cl * 8);
        dptr[0] = make_float4(acc[0] * inv, acc[1] * inv, acc[2] * inv, acc[3] * inv);
        dptr[1] = make_float4(acc[4] * inv, acc[5] * inv, acc[6] * inv, acc[7] * inv);
    }
}

// ---- y[g][c] = sum_k x[g][k]*W[c][k] ----
// MODE0: write bf16 only (y1). MODE1: v += aggr+bias, relu; write f32 h AND bf16 hb.
template <int MODE>
__global__ __launch_bounds__(TPB) void lin128to64_kernel(
    const float* __restrict__ x, const float* __restrict__ W,
    const float* __restrict__ aggr, const float* __restrict__ bias,
    float* __restrict__ outf, ushort_t* __restrict__ outb, int n) {
    __shared__ float Ws[64 * 128];  // Ws[c*128 + (k ^ (c&31))] = W[c][k]
    __shared__ float xs[64 * 128];  // xs[r*128 + (k ^ ((r&3)<<3))] = x[node0+r][k]
    const int tid = threadIdx.x;
    const int node0 = blockIdx.x * 64;

    for (int idx = tid; idx < 64 * 128; idx += TPB) {
        int r = idx >> 7, k = idx & 127;
        Ws[(r << 7) + (k ^ (r & 31))] = W[idx];
    }
    for (int idx = tid; idx < 64 * 128; idx += TPB) {
        int r = idx >> 7, k = idx & 127;
        int g = node0 + r;
        xs[(r << 7) + (k ^ ((r & 3) << 3))] = (g < n) ? x[(long long)g * 128 + k] : 0.0f;
    }
    __syncthreads();

    const int cg = tid & 15;
    const int ng = tid >> 4;
    float acc[4][4];
#pragma unroll
    for (int i = 0; i < 4; ++i)
#pragma unroll
        for (int j = 0; j < 4; ++j) acc[i][j] = 0.0f;

    const int xsw = (ng & 3) << 3;
    int wbase[4], wsw[4], xbase[4];
#pragma unroll
    for (int j = 0; j < 4; ++j) {
        int c = cg + 16 * j;
        wbase[j] = c << 7;
        wsw[j] = c & 31;
    }
#pragma unroll
    for (int i = 0; i < 4; ++i) xbase[i] = (ng + 16 * i) << 7;

#pragma unroll 4
    for (int k = 0; k < 128; ++k) {
        float xv[4], wv[4];
        int kx = k ^ xsw;
#pragma unroll
        for (int i = 0; i < 4; ++i) xv[i] = xs[xbase[i] + kx];
#pragma unroll
        for (int j = 0; j < 4; ++j) wv[j] = Ws[wbase[j] + (k ^ wsw[j])];
#pragma unroll
        for (int i = 0; i < 4; ++i)
#pragma unroll
            for (int j = 0; j < 4; ++j) acc[i][j] += xv[i] * wv[j];
    }

#pragma unroll
    for (int i = 0; i < 4; ++i) {
        int g = node0 + ng + 16 * i;
        if (g >= n) continue;
#pragma unroll
        for (int j = 0; j < 4; ++j) {
            int c = cg + 16 * j;
            float v = acc[i][j];
            if (MODE == 1) {
                v += aggr[g * 64 + c] + bias[c];
                v = fmaxf(v, 0.0f);
                outf[(long long)g * 64 + c] = v;
            }
            outb[(long long)g * 64 + c] = f2bf(v);
        }
    }
}

// ---- out[g][C] = sum_k m2[g][k]*Wl[C][k] + sum_k h[g][k]*Wr[C][k] + b[C] ----
__global__ __launch_bounds__(TPB) void out_kernel(
    const float* __restrict__ m2, const float* __restrict__ h,
    const float* __restrict__ Wl, const float* __restrict__ Wr,
    const float* __restrict__ bias, float* __restrict__ out, int n) {
    __shared__ float Wls[64 * 64];
    __shared__ float Wrs[64 * 64];
    __shared__ float ams[64 * 64];
    __shared__ float hhs[64 * 64];
    const int tid = threadIdx.x;
    const int node0 = blockIdx.x * 64;
    const int chalf = blockIdx.y * 64;

    for (int idx = tid; idx < 64 * 64; idx += TPB) {
        int c = idx >> 6, k = idx & 63;
        int sw = (c << 6) + (k ^ (c & 31));
        Wls[sw] = Wl[(chalf + c) * 64 + k];
        Wrs[sw] = Wr[(chalf + c) * 64 + k];
    }
    for (int idx = tid; idx < 64 * 64; idx += TPB) {
        int r = idx >> 6, k = idx & 63;
        int g = node0 + r;
        float av = 0.0f, hv = 0.0f;
        if (g < n) {
            av = m2[(long long)g * 64 + k];
            hv = h[(long long)g * 64 + k];
        }
        ams[(r << 6) + k] = av;
        hhs[(r << 6) + k] = hv;
    }
    __syncthreads();

    const int cg = tid & 31;
    const int ng = tid >> 5;
    float acc[8][2];
#pragma unroll
    for (int i = 0; i < 8; ++i) { acc[i][0] = 0.0f; acc[i][1] = 0.0f; }
    const int wb0 = cg << 6;
    const int wb1 = (cg + 32) << 6;

#pragma unroll 4
    for (int k = 0; k < 64; ++k) {
        int kk = k ^ cg;
        float wl0 = Wls[wb0 + kk], wl1 = Wls[wb1 + kk];
        float wr0 = Wrs[wb0 + kk], wr1 = Wrs[wb1 + kk];
#pragma unroll
        for (int i = 0; i < 8; ++i) {
            int r = ng + 8 * i;
            float av = ams[(r << 6) + k];
            float hv = hhs[(r << 6) + k];
            acc[i][0] += av * wl0 + hv * wr0;
            acc[i][1] += av * wl1 + hv * wr1;
        }
    }

#pragma unroll
    for (int i = 0; i < 8; ++i) {
        int g = node0 + ng + 8 * i;
        if (g >= n) continue;
        long long base = (long long)g * 128 + chalf;
        out[base + cg] = acc[i][0] + bias[chalf + cg];
        out[base + cg + 32] = acc[i][1] + bias[chalf + cg + 32];
    }
}

extern "C" void kernel_launch(void* const* d_in, const int* in_sizes, int n_in,
                              void* d_out, int out_size, void* d_ws, size_t ws_size,
                              hipStream_t stream) {
    const float* x = (const float*)d_in[0];
    const int* ei = (const int*)d_in[1];
    const float* Wl1 = (const float*)d_in[2];
    const float* Wr1 = (const float*)d_in[3];
    const float* b1 = (const float*)d_in[4];
    const float* Wl2 = (const float*)d_in[5];
    const float* Wr2 = (const float*)d_in[6];
    const float* b2 = (const float*)d_in[7];
    float* out = (float*)d_out;

    const int n = in_sizes[0] / 128;   // 100000
    const int E = in_sizes[1] / 2;     // 1600000
    const int* src = ei;
    const int* dst = ei + E;
    const int NB = (n + 255) >> BK_SH; // buckets of 256 nodes

    // workspace (4B units, 64-aligned):
    // bcnt[512] | bbase[512] | bcursor[512] | rs[n+1] | recs[E] | perm[E]
    //   | fb (n*64 bf16 = n*32 u32) | meanf[n*64 f32] | h[n*64 f32]
    char* wsb = (char*)d_ws;
    auto A = [](size_t v) { return (v + 63) & ~(size_t)63; };
    int* bcnt = (int*)wsb;                         size_t o = NBMAX;
    int* bbase = (int*)wsb + o;                    o += NBMAX;
    int* bcursor = (int*)wsb + o;                  o += NBMAX;
    int* rs = (int*)wsb + o;                       o += A(n + 1);
    uint_t* recs = (uint_t*)((int*)wsb + o);       o += A(E);
    int* perm = (int*)wsb + o;                     o += A(E);
    ushort_t* fb = (ushort_t*)((int*)wsb + o);     o += A((size_t)n * 32);
    float* meanf = (float*)wsb + o;                o += (size_t)n * 64;
    float* h = (float*)wsb + o;

    // ---- CSR build via two-level binning ----
    hipMemsetAsync(bcnt, 0, NBMAX * sizeof(int), stream);
    bucket_hist_kernel<<<512, TPB, 0, stream>>>(dst, bcnt, E, NB);
    bucket_scan_kernel<<<1, NBMAX, 0, stream>>>(bcnt, bbase, bcursor, NB, rs, n, E);
    bin_scatter_kernel<<<(E + TILE - 1) / TILE, TPB, 0, stream>>>(src, dst, bcursor, recs, E, NB);
    bucket_build_kernel<<<NB, TPB, 0, stream>>>(recs, bbase, bcnt, rs, perm, n);

    const int gblocks = (n + 63) / 64;
    const int mblocks = (int)(((long long)n * 64 + TPB - 1) / TPB);

    // y1b = bf16(x @ W_l1.T)
    lin128to64_kernel<0><<<gblocks, TPB, 0, stream>>>(x, Wl1, nullptr, nullptr,
                                                      nullptr, fb, n);
    // meanf = csr_mean(y1b)
    csr_mean_bf16_kernel<<<mblocks, TPB, 0, stream>>>(fb, rs, perm, meanf, n);
    // h = relu(meanf + b1 + x @ W_r1.T); hb = bf16(h) (overwrites y1b -- dead)
    lin128to64_kernel<1><<<gblocks, TPB, 0, stream>>>(x, Wr1, meanf, b1, h, fb, n);
    // meanf = csr_mean(hb) (meanf dead after lin<1>)
    csr_mean_bf16_kernel<<<mblocks, TPB, 0, stream>>>(fb, rs, perm, meanf, n);
    // out = meanf @ W_l2.T + b2 + h @ W_r2.T
    dim3 og(gblocks, 2);
    out_kernel<<<og, TPB, 0, stream>>>(meanf, h, Wl2, Wr2, b2, out, n);
}

// Round 6
// 316.589 us; speedup vs baseline: 2.4416x; 1.5925x over previous
//
#include <hip/hip_runtime.h>

#define TPB 256
#define BK_SH 8           // 256 nodes per bucket
#define NBMAX 512         // max buckets (n <= 131072)
#define TILE 4096         // edges per bin_scatter tile
#define CAP 8192          // LDS staging capacity per bucket (records)

typedef unsigned short ushort_t;
typedef unsigned int uint_t;
typedef __attribute__((ext_vector_type(8))) __bf16 bf8v;
typedef __attribute__((ext_vector_type(4))) float f4v;

__device__ inline ushort_t f2bf(float f) {  // round-to-nearest-even bf16
    uint_t u = __float_as_uint(f);
    return (ushort_t)((u + 0x7FFFu + ((u >> 16) & 1u)) >> 16);
}
__device__ inline uint_t pack2(float a, float b) {
    return (uint_t)f2bf(a) | ((uint_t)f2bf(b) << 16);
}

// ========== K1: bucket histogram (dst >> 8), LDS-aggregated ==========
__global__ __launch_bounds__(TPB) void bucket_hist_kernel(const int* __restrict__ dst,
                                                          int* __restrict__ bcnt,
                                                          int E, int NB) {
    __shared__ int h[NBMAX];
    for (int i = threadIdx.x; i < NBMAX; i += TPB) h[i] = 0;
    __syncthreads();
    int stride = gridDim.x * TPB;
    for (int e = blockIdx.x * TPB + threadIdx.x; e < E; e += stride)
        atomicAdd(&h[dst[e] >> BK_SH], 1);
    __syncthreads();
    for (int i = threadIdx.x; i < NB; i += TPB)
        if (h[i]) atomicAdd(&bcnt[i], h[i]);
}

// ========== K2: scan bucket counts -> bases + cursors; rs[n] = E ==========
__global__ __launch_bounds__(NBMAX) void bucket_scan_kernel(const int* __restrict__ bcnt,
                                                            int* __restrict__ bbase,
                                                            int* __restrict__ bcursor,
                                                            int NB, int* __restrict__ rs,
                                                            int n, int E) {
    __shared__ int s[NBMAX];
    const int t = threadIdx.x;
    int v = (t < NB) ? bcnt[t] : 0;
    s[t] = v;
    __syncthreads();
    for (int off = 1; off < NBMAX; off <<= 1) {
        int a = (t >= off) ? s[t - off] : 0;
        __syncthreads();
        s[t] += a;
        __syncthreads();
    }
    if (t < NB) { int ex = s[t] - v; bbase[t] = ex; bcursor[t] = ex; }
    if (t == 0) rs[n] = E;
}

// ========== K3: tile-sort edges by bucket in LDS, flush contiguous runs ==========
// record = (src << 8) | (dst & 255)
__global__ __launch_bounds__(TPB) void bin_scatter_kernel(const int* __restrict__ src,
                                                          const int* __restrict__ dst,
                                                          int* __restrict__ bcursor,
                                                          uint_t* __restrict__ recs,
                                                          int E, int NB) {
    __shared__ uint_t rec[TILE];
    __shared__ ushort_t bb[TILE];
    __shared__ int hist[NBMAX];
    __shared__ int start[NBMAX];
    __shared__ int cur[NBMAX];
    __shared__ int gbase[NBMAX];
    __shared__ int ss[TPB];
    const int tid = threadIdx.x;
    const int t0 = blockIdx.x * TILE;
    const int cnt = min(TILE, E - t0);
    for (int i = tid; i < NBMAX; i += TPB) hist[i] = 0;
    __syncthreads();

    int myS[16], myD[16];
#pragma unroll
    for (int j = 0; j < 16; ++j) {
        int e = t0 + j * TPB + tid;
        if (e < E) {
            myS[j] = src[e];
            myD[j] = dst[e];
            atomicAdd(&hist[myD[j] >> BK_SH], 1);
        } else {
            myD[j] = -1;
        }
    }
    __syncthreads();

    int h0 = hist[2 * tid], h1 = hist[2 * tid + 1];
    int sum2 = h0 + h1;
    ss[tid] = sum2;
    __syncthreads();
    for (int off = 1; off < TPB; off <<= 1) {
        int a = (tid >= off) ? ss[tid - off] : 0;
        __syncthreads();
        ss[tid] += a;
        __syncthreads();
    }
    int ex = ss[tid] - sum2;
    start[2 * tid] = ex;
    start[2 * tid + 1] = ex + h0;
    cur[2 * tid] = ex;
    cur[2 * tid + 1] = ex + h0;
    __syncthreads();

#pragma unroll
    for (int j = 0; j < 16; ++j) {
        if (myD[j] >= 0) {
            int b = myD[j] >> BK_SH;
            int p = atomicAdd(&cur[b], 1);
            rec[p] = ((uint_t)myS[j] << BK_SH) | (uint_t)(myD[j] & ((1 << BK_SH) - 1));
            bb[p] = (ushort_t)b;
        }
    }
    __syncthreads();

    for (int b = tid; b < NB; b += TPB) {
        int c = hist[b];
        gbase[b] = c ? atomicAdd(&bcursor[b], c) : 0;
    }
    __syncthreads();

    for (int i = tid; i < cnt; i += TPB) {
        int b = bb[i];
        recs[gbase[b] + (i - start[b])] = rec[i];
    }
}

// ========== K4: per-bucket: per-node counts, rs, build perm in LDS, flush ==========
__global__ __launch_bounds__(TPB) void bucket_build_kernel(const uint_t* __restrict__ recs,
                                                           const int* __restrict__ bbase,
                                                           const int* __restrict__ bcnt,
                                                           int* __restrict__ rs,
                                                           int* __restrict__ perm, int n) {
    __shared__ int nh[TPB];
    __shared__ int ncur[TPB];
    __shared__ int sscan[TPB];
    __shared__ uint_t stage[CAP];
    const int b = blockIdx.x;
    const int tid = threadIdx.x;
    const int gb = bbase[b];
    const int cnt = bcnt[b];
    nh[tid] = 0;
    __syncthreads();
    for (int i = tid; i < cnt; i += TPB)
        atomicAdd(&nh[recs[gb + i] & 255], 1);
    __syncthreads();
    int v = nh[tid];
    sscan[tid] = v;
    __syncthreads();
    for (int off = 1; off < TPB; off <<= 1) {
        int a = (tid >= off) ? sscan[tid - off] : 0;
        __syncthreads();
        sscan[tid] += a;
        __syncthreads();
    }
    int ex = sscan[tid] - v;
    int g = (b << BK_SH) + tid;
    if (g < n) rs[g] = gb + ex;
    ncur[tid] = ex;
    __syncthreads();
    if (cnt <= CAP) {
        for (int i = tid; i < cnt; i += TPB) {
            uint_t r = recs[gb + i];
            int p = atomicAdd(&ncur[r & 255], 1);
            stage[p] = r >> BK_SH;
        }
        __syncthreads();
        for (int i = tid; i < cnt; i += TPB)
            perm[gb + i] = (int)stage[i];
    } else {
        for (int i = tid; i < cnt; i += TPB) {
            uint_t r = recs[gb + i];
            int p = atomicAdd(&ncur[r & 255], 1);
            perm[gb + p] = (int)(r >> BK_SH);
        }
    }
}

// ========== converts ==========
__global__ __launch_bounds__(TPB) void cvt_x_kernel(const float* __restrict__ x,
                                                    ushort_t* __restrict__ xb,
                                                    long long total) {
    long long i = ((long long)blockIdx.x * TPB + threadIdx.x) * 8;
    if (i >= total) return;
    float4 v0 = *(const float4*)(x + i);
    float4 v1 = *(const float4*)(x + i + 4);
    uint4 o;
    o.x = pack2(v0.x, v0.y);
    o.y = pack2(v0.z, v0.w);
    o.z = pack2(v1.x, v1.y);
    o.w = pack2(v1.z, v1.w);
    *(uint4*)(xb + i) = o;
}

// Wl1b/Wr1b: [64][128] bf16. Wcat: [128][128] bf16, k<64 from Wl2, k>=64 from Wr2.
__global__ __launch_bounds__(TPB) void cvt_w_kernel(const float* __restrict__ Wl1,
                                                    const float* __restrict__ Wr1,
                                                    const float* __restrict__ Wl2,
                                                    const float* __restrict__ Wr2,
                                                    ushort_t* __restrict__ wl1b,
                                                    ushort_t* __restrict__ wr1b,
                                                    ushort_t* __restrict__ wcat) {
    int i = blockIdx.x * TPB + threadIdx.x;  // 0..16383
    if (i < 8192) {
        wl1b[i] = f2bf(Wl1[i]);
        wr1b[i] = f2bf(Wr1[i]);
    }
    if (i < 16384) {
        int c = i >> 7, k = i & 127;
        wcat[i] = (k < 64) ? f2bf(Wl2[c * 64 + k]) : f2bf(Wr2[c * 64 + (k - 64)]);
    }
}

// ========== MFMA GEMM: y[g][c] = sum_k xb[g][k]*Wb[c][k], K=128, N=64 ==========
// MODE0: outb = bf16(y). MODE1: outb = bf16(relu(y + aggr + bias)).
// Block = 4 waves x 32 nodes = 128 nodes. No LDS: A/B frags are direct 16B loads
// (mfma_f32_16x16x32_bf16: lane holds 8 k-contiguous elems; k=quad*8, row/col=lane&15).
template <int MODE>
__global__ __launch_bounds__(TPB) void lin_mfma_kernel(
    const ushort_t* __restrict__ xb, const ushort_t* __restrict__ Wb,
    const float* __restrict__ aggr, const float* __restrict__ bias,
    ushort_t* __restrict__ outb, int n) {
    const int wave = threadIdx.x >> 6;
    const int lane = threadIdx.x & 63;
    const int l16 = lane & 15;
    const int quad = lane >> 4;
    const int node0 = blockIdx.x * 128 + wave * 32;
    const int koff = quad * 8;

    bf8v wb[4][4];
#pragma unroll
    for (int ct = 0; ct < 4; ++ct)
#pragma unroll
        for (int kt = 0; kt < 4; ++kt)
            wb[ct][kt] = *(const bf8v*)(Wb + (ct * 16 + l16) * 128 + kt * 32 + koff);

    f4v acc[2][4];
#pragma unroll
    for (int mt = 0; mt < 2; ++mt)
#pragma unroll
        for (int ct = 0; ct < 4; ++ct) acc[mt][ct] = (f4v)(0.0f);

#pragma unroll
    for (int mt = 0; mt < 2; ++mt) {
        int row = node0 + mt * 16 + l16;
        row = min(row, n - 1);
        bf8v a[4];
#pragma unroll
        for (int kt = 0; kt < 4; ++kt)
            a[kt] = *(const bf8v*)(xb + (long long)row * 128 + kt * 32 + koff);
#pragma unroll
        for (int ct = 0; ct < 4; ++ct)
#pragma unroll
            for (int kt = 0; kt < 4; ++kt)
                acc[mt][ct] = __builtin_amdgcn_mfma_f32_16x16x32_bf16(
                    a[kt], wb[ct][kt], acc[mt][ct], 0, 0, 0);
    }

    // D layout: col = lane&15, row = quad*4 + r
#pragma unroll
    for (int ct = 0; ct < 4; ++ct) {
        const int col = ct * 16 + l16;
        float bv = (MODE == 1) ? bias[col] : 0.0f;
#pragma unroll
        for (int mt = 0; mt < 2; ++mt) {
            int rbase = node0 + mt * 16 + quad * 4;
#pragma unroll
            for (int r = 0; r < 4; ++r) {
                int g = rbase + r;
                if (g >= n) continue;
                float v = acc[mt][ct][r];
                if (MODE == 1) v = fmaxf(v + aggr[(long long)g * 64 + col] + bv, 0.0f);
                outb[(long long)g * 64 + col] = f2bf(v);
            }
        }
    }
}

// ========== MFMA out: out[g][C] = [m2b|hb] @ Wcat^T + b2, K=128, N=128 ==========
// Block = 4 waves; each wave owns 32 cols, all waves cover the same 64 nodes.
__global__ __launch_bounds__(TPB) void out_mfma_kernel(
    const ushort_t* __restrict__ m2b, const ushort_t* __restrict__ hb,
    const ushort_t* __restrict__ Wc, const float* __restrict__ b2,
    float* __restrict__ out, int n) {
    const int wave = threadIdx.x >> 6;
    const int lane = threadIdx.x & 63;
    const int l16 = lane & 15;
    const int quad = lane >> 4;
    const int cb = wave * 32;
    const int node0 = blockIdx.x * 64;
    const int koff = quad * 8;

    bf8v wb[2][4];
#pragma unroll
    for (int ct = 0; ct < 2; ++ct)
#pragma unroll
        for (int kt = 0; kt < 4; ++kt)
            wb[ct][kt] = *(const bf8v*)(Wc + (cb + ct * 16 + l16) * 128 + kt * 32 + koff);

    f4v acc[4][2];
#pragma unroll
    for (int mt = 0; mt < 4; ++mt)
#pragma unroll
        for (int ct = 0; ct < 2; ++ct) acc[mt][ct] = (f4v)(0.0f);

#pragma unroll
    for (int mt = 0; mt < 4; ++mt) {
        int row = node0 + mt * 16 + l16;
        row = min(row, n - 1);
        bf8v a[4];
        a[0] = *(const bf8v*)(m2b + (long long)row * 64 + koff);
        a[1] = *(const bf8v*)(m2b + (long long)row * 64 + 32 + koff);
        a[2] = *(const bf8v*)(hb + (long long)row * 64 + koff);
        a[3] = *(const bf8v*)(hb + (long long)row * 64 + 32 + koff);
#pragma unroll
        for (int ct = 0; ct < 2; ++ct)
#pragma unroll
            for (int kt = 0; kt < 4; ++kt)
                acc[mt][ct] = __builtin_amdgcn_mfma_f32_16x16x32_bf16(
                    a[kt], wb[ct][kt], acc[mt][ct], 0, 0, 0);
    }

#pragma unroll
    for (int ct = 0; ct < 2; ++ct) {
        const int col = cb + ct * 16 + l16;
        const float bv = b2[col];
#pragma unroll
        for (int mt = 0; mt < 4; ++mt) {
            int rbase = node0 + mt * 16 + quad * 4;
#pragma unroll
            for (int r = 0; r < 4; ++r) {
                int g = rbase + r;
                if (g >= n) continue;
                out[(long long)g * 128 + col] = acc[mt][ct][r] + bv;
            }
        }
    }
}

// ====== mean aggregation over bf16 feature rows, via CSR ======
// One wave per dst node. lane = o*8 + cl: oct o handles edge slot e+o,
// lane cl covers 16B = 8 bf16 cols. OUTBF: write bf16 row, else f32 row.
template <int OUTBF>
__global__ __launch_bounds__(TPB) void csr_mean_bf16_kernel(
    const ushort_t* __restrict__ feat, const int* __restrict__ rs,
    const int* __restrict__ perm, float* __restrict__ outf,
    ushort_t* __restrict__ outb, int n) {
    int w = (int)(((long long)blockIdx.x * TPB + threadIdx.x) >> 6);
    if (w >= n) return;
    const int lane = threadIdx.x & 63;
    const int o = lane >> 3;
    const int cl = lane & 7;
    const int beg = rs[w], end = rs[w + 1];
    float acc[8];
#pragma unroll
    for (int j = 0; j < 8; ++j) acc[j] = 0.0f;
    for (int e = beg + o; e < end; e += 8) {
        int s = perm[e];
        uint4 v = ((const uint4*)(feat + (long long)s * 64))[cl];
        acc[0] += __uint_as_float(v.x << 16);
        acc[1] += __uint_as_float(v.x & 0xFFFF0000u);
        acc[2] += __uint_as_float(v.y << 16);
        acc[3] += __uint_as_float(v.y & 0xFFFF0000u);
        acc[4] += __uint_as_float(v.z << 16);
        acc[5] += __uint_as_float(v.z & 0xFFFF0000u);
        acc[6] += __uint_as_float(v.w << 16);
        acc[7] += __uint_as_float(v.w & 0xFFFF0000u);
    }
#pragma unroll
    for (int off = 8; off < 64; off <<= 1)
#pragma unroll
        for (int j = 0; j < 8; ++j) acc[j] += __shfl_xor(acc[j], off, 64);
    if (lane < 8) {
        float d = (float)(end - beg);
        float inv = d > 0.f ? 1.f / d : 0.f;
        if (OUTBF) {
            uint4 o4;
            o4.x = pack2(acc[0] * inv, acc[1] * inv);
            o4.y = pack2(acc[2] * inv, acc[3] * inv);
            o4.z = pack2(acc[4] * inv, acc[5] * inv);
            o4.w = pack2(acc[6] * inv, acc[7] * inv);
            ((uint4*)(outb + (long long)w * 64))[cl] = o4;
        } else {
            float4* dptr = (float4*)(outf + (long long)w * 64 + cl * 8);
            dptr[0] = make_float4(acc[0] * inv, acc[1] * inv, acc[2] * inv, acc[3] * inv);
            dptr[1] = make_float4(acc[4] * inv, acc[5] * inv, acc[6] * inv, acc[7] * inv);
        }
    }
}

extern "C" void kernel_launch(void* const* d_in, const int* in_sizes, int n_in,
                              void* d_out, int out_size, void* d_ws, size_t ws_size,
                              hipStream_t stream) {
    const float* x = (const float*)d_in[0];
    const int* ei = (const int*)d_in[1];
    const float* Wl1 = (const float*)d_in[2];
    const float* Wr1 = (const float*)d_in[3];
    const float* b1 = (const float*)d_in[4];
    const float* Wl2 = (const float*)d_in[5];
    const float* Wr2 = (const float*)d_in[6];
    const float* b2 = (const float*)d_in[7];
    float* out = (float*)d_out;

    const int n = in_sizes[0] / 128;   // 100000
    const int E = in_sizes[1] / 2;     // 1600000
    const int* src = ei;
    const int* dst = ei + E;
    const int NB = (n + 255) >> BK_SH;

    // workspace (4B units, 64-aligned):
    // bcnt|bbase|bcursor[512 ea] | rs[n+1] | recs[E] | perm[E] | xb[n*128 bf16]
    //   | wl1b | wr1b | wcat | fb[n*64 bf16 y1b->hb] | meanf[n*64 f32; m2b aliases]
    char* wsb = (char*)d_ws;
    auto A = [](size_t v) { return (v + 63) & ~(size_t)63; };
    int* bcnt = (int*)wsb;                         size_t o = NBMAX;
    int* bbase = (int*)wsb + o;                    o += NBMAX;
    int* bcursor = (int*)wsb + o;                  o += NBMAX;
    int* rs = (int*)wsb + o;                       o += A(n + 1);
    uint_t* recs = (uint_t*)((int*)wsb + o);       o += A(E);
    int* perm = (int*)wsb + o;                     o += A(E);
    ushort_t* xb = (ushort_t*)((int*)wsb + o);     o += A((size_t)n * 64);
    ushort_t* wl1b = (ushort_t*)((int*)wsb + o);   o += 4096;
    ushort_t* wr1b = (ushort_t*)((int*)wsb + o);   o += 4096;
    ushort_t* wcat = (ushort_t*)((int*)wsb + o);   o += 8192;
    ushort_t* fb = (ushort_t*)((int*)wsb + o);     o += A((size_t)n * 32);
    float* meanf = (float*)wsb + o;                // n*64 f32
    ushort_t* m2b = (ushort_t*)meanf;              // aliases meanf (meanf dead by mean2)

    // ---- CSR build via two-level binning ----
    hipMemsetAsync(bcnt, 0, NBMAX * sizeof(int), stream);
    bucket_hist_kernel<<<512, TPB, 0, stream>>>(dst, bcnt, E, NB);
    bucket_scan_kernel<<<1, NBMAX, 0, stream>>>(bcnt, bbase, bcursor, NB, rs, n, E);
    bin_scatter_kernel<<<(E + TILE - 1) / TILE, TPB, 0, stream>>>(src, dst, bcursor, recs, E, NB);
    bucket_build_kernel<<<NB, TPB, 0, stream>>>(recs, bbase, bcnt, rs, perm, n);

    // ---- bf16 conversions ----
    long long xtot = (long long)n * 128;
    cvt_x_kernel<<<(int)((xtot / 8 + TPB - 1) / TPB), TPB, 0, stream>>>(x, xb, xtot);
    cvt_w_kernel<<<64, TPB, 0, stream>>>(Wl1, Wr1, Wl2, Wr2, wl1b, wr1b, wcat);

    const int lblocks = (n + 127) / 128;
    const int mblocks = (int)(((long long)n * 64 + TPB - 1) / TPB);
    const int oblocks = (n + 63) / 64;

    // y1b = bf16(xb @ Wl1^T)
    lin_mfma_kernel<0><<<lblocks, TPB, 0, stream>>>(xb, wl1b, nullptr, nullptr, fb, n);
    // meanf = mean(y1b)  [f32]
    csr_mean_bf16_kernel<0><<<mblocks, TPB, 0, stream>>>(fb, rs, perm, meanf, nullptr, n);
    // hb = bf16(relu(meanf + b1 + xb @ Wr1^T))  (overwrites y1b -- dead)
    lin_mfma_kernel<1><<<lblocks, TPB, 0, stream>>>(xb, wr1b, meanf, b1, fb, n);
    // m2b = bf16(mean(hb))  (meanf dead -> aliased)
    csr_mean_bf16_kernel<1><<<mblocks, TPB, 0, stream>>>(fb, rs, perm, nullptr, m2b, n);
    // out = [m2b|hb] @ wcat^T + b2
    out_mfma_kernel<<<oblocks, TPB, 0, stream>>>(m2b, fb, wcat, b2, out, n);
}